// Round 8
// baseline (936.668 us; speedup 1.0000x reference)
//
#include <hip/hip_runtime.h>

#define NN 512
#define BSZ 64
#define TTOT 200
#define NSTEP 199
#define DD 32

typedef __attribute__((ext_vector_type(8))) short bf16x8;
typedef __attribute__((ext_vector_type(8))) int i32x8;
typedef __attribute__((ext_vector_type(4))) float f32x4;
typedef __attribute__((ext_vector_type(4))) unsigned int u32x4;

__device__ __forceinline__ float bf2f(unsigned short u) {
  union { unsigned int i; float f; } v; v.i = ((unsigned int)u) << 16; return v.f;
}
__device__ __forceinline__ unsigned short f2bf(float f) {  // RNE
  unsigned int b = __float_as_uint(f);
  return (unsigned short)((b + 0x7fffu + ((b >> 16) & 1u)) >> 16);
}
__device__ __forceinline__ unsigned int pk_trunc(float hi, float lo) {
  return __builtin_amdgcn_perm(__float_as_uint(hi), __float_as_uint(lo), 0x07060302u);
}
// f32 -> OCP e4m3 (RNE on normals; flush tiny to 0; clamp 448)
__device__ __forceinline__ unsigned char e4m3(float x) {
  float a = fabsf(x);
  unsigned int s = (__float_as_uint(x) >> 24) & 0x80u;
  if (a < 0.01171875f) return (unsigned char)s;
  a = fminf(a, 448.0f);
  unsigned int u = __float_as_uint(a);
  unsigned int keep = (u >> 20) & 7u;
  unsigned int rest = u & 0xFFFFFu;
  unsigned int base = (((u >> 23) - 120u) << 3) | keep;
  unsigned int rnd = (rest > 0x80000u) || (rest == 0x80000u && (keep & 1u));
  return (unsigned char)(s | (base + rnd));
}
__device__ __forceinline__ float dec8(unsigned char x) {  // e4m3 -> f32
  int e = (x >> 3) & 15, m = x & 7;
  float v = e ? ldexpf(8.f + (float)m, e - 10) : ldexpf((float)m, -9);
  return (x & 0x80) ? -v : v;
}
__device__ __forceinline__ float rlane(float v, int l) {
  return __int_as_float(__builtin_amdgcn_readlane(__float_as_int(v), l));
}

// ---------------------------------------------------------------------------
// Transpose+convert: A1 (f32 [b][r][c]) -> A1T (bf16 [b][c][r]).  [proven]
// ---------------------------------------------------------------------------
__global__ __launch_bounds__(256) void transpose_kernel(
    const float* __restrict__ A1, unsigned short* __restrict__ A1T) {
  const int b = blockIdx.x, ct = blockIdx.y * 64, rt = blockIdx.z * 64;
  const int t = threadIdx.x;
  __shared__ unsigned int tl[64][33];
  {
    const int rp = t >> 3, cs = (t & 7) * 8;
    const float* p0 = A1 + (size_t)b * NN * NN + (size_t)(rt + 2 * rp) * NN + ct + cs;
    f32x4 a0 = *(const f32x4*)p0, a1 = *(const f32x4*)(p0 + 4);
    f32x4 b0 = *(const f32x4*)(p0 + NN), b1 = *(const f32x4*)(p0 + NN + 4);
#pragma unroll
    for (int j = 0; j < 4; ++j) {
      tl[cs + j][rp] = pk_trunc(b0[j], a0[j]);
      tl[cs + 4 + j][rp] = pk_trunc(b1[j], a1[j]);
    }
  }
  __syncthreads();
  {
    const int c = t >> 2, rps = (t & 3) * 8;
    unsigned int v[8];
#pragma unroll
    for (int j = 0; j < 8; ++j) v[j] = tl[c][rps + j];
    unsigned int* dst = (unsigned int*)(A1T + (size_t)b * NN * NN +
                                        (size_t)(ct + c) * NN + rt) + rps;
    *(u32x4*)dst = u32x4{v[0], v[1], v[2], v[3]};
    *(u32x4*)(dst + 4) = u32x4{v[4], v[5], v[6], v[7]};
  }
}

// ---------------------------------------------------------------------------
// GEMM 1 fast: A2 = A1@A1 bf16 out.  [proven]
// ---------------------------------------------------------------------------
__global__ __launch_bounds__(256) void gemm_a2_fast(
    const float* __restrict__ A1, const unsigned short* __restrict__ A1T,
    unsigned short* __restrict__ A2) {
  const int b = blockIdx.x, tn = blockIdx.y, tm = blockIdx.z;
  const int tid = threadIdx.x, lane = tid & 63, w = tid >> 6;
  const int q = lane >> 4, ln = lane & 15;
  const size_t Ao = (size_t)b * NN * NN;
  f32x4 zero = {0.f, 0.f, 0.f, 0.f};
  f32x4 acc[4] = {zero, zero, zero, zero};
  const float* ap = A1 + Ao + (size_t)(tm * 64 + w * 16 + ln) * NN + q * 8;
  const unsigned short* bt = A1T + Ao;
  for (int k0 = 0; k0 < NN; k0 += 32) {
    f32x4 x0 = *(const f32x4*)(ap + k0);
    f32x4 x1 = *(const f32x4*)(ap + k0 + 4);
    union { bf16x8 v; unsigned int u[4]; } af;
    af.u[0] = pk_trunc(x0[1], x0[0]);
    af.u[1] = pk_trunc(x0[3], x0[2]);
    af.u[2] = pk_trunc(x1[1], x1[0]);
    af.u[3] = pk_trunc(x1[3], x1[2]);
#pragma unroll
    for (int i = 0; i < 4; ++i) {
      bf16x8 bv = *(const bf16x8*)(bt + (size_t)(tn * 64 + i * 16 + ln) * NN + k0 + q * 8);
      acc[i] = __builtin_amdgcn_mfma_f32_16x16x32_bf16(af.v, bv, acc[i], 0, 0, 0);
    }
  }
  unsigned short* Cb = A2 + Ao;
#pragma unroll
  for (int i = 0; i < 4; ++i) {
    int col = tn * 64 + i * 16 + ln;
#pragma unroll
    for (int r = 0; r < 4; ++r) {
      int row = tm * 64 + w * 16 + q * 4 + r;
      Cb[(size_t)row * NN + col] = f2bf(acc[i][r]);
    }
  }
}

// ---------------------------------------------------------------------------
// GEMM 2 fast: A3 = A2@A1; M*2^20 -> e4m3 into M8T[b][col][k], u32-packed.
// ---------------------------------------------------------------------------
__global__ __launch_bounds__(256) void gemm_m_fast(
    const float* __restrict__ A1, const unsigned short* __restrict__ A1T,
    const unsigned short* __restrict__ A2, unsigned char* __restrict__ M8T) {
  const int b = blockIdx.x, tn = blockIdx.y, tm = blockIdx.z;
  const int tid = threadIdx.x, lane = tid & 63, w = tid >> 6;
  const int q = lane >> 4, ln = lane & 15;
  const size_t Ao = (size_t)b * NN * NN;
  const unsigned short* A2b = A2 + Ao;
  f32x4 zero = {0.f, 0.f, 0.f, 0.f};
  f32x4 acc[4] = {zero, zero, zero, zero};
  const unsigned short* ap = A2b + (size_t)(tm * 64 + w * 16 + ln) * NN + q * 8;
  const unsigned short* bt = A1T + Ao;
  for (int k0 = 0; k0 < NN; k0 += 32) {
    bf16x8 af = *(const bf16x8*)(ap + k0);
#pragma unroll
    for (int i = 0; i < 4; ++i) {
      bf16x8 bv = *(const bf16x8*)(bt + (size_t)(tn * 64 + i * 16 + ln) * NN + k0 + q * 8);
      acc[i] = __builtin_amdgcn_mfma_f32_16x16x32_bf16(af, bv, acc[i], 0, 0, 0);
    }
  }
  const float c1 = 1048576.f / (3.f * 512.f * 512.f);
  const float c2 = c1 / 512.f;
  const float c3 = c2 / 512.f;
  unsigned char* Mb = M8T + Ao;
#pragma unroll
  for (int i = 0; i < 4; ++i) {
    int col = tn * 64 + i * 16 + ln;
    unsigned int pk = 0;
#pragma unroll
    for (int r = 0; r < 4; ++r) {
      int row = tm * 64 + w * 16 + q * 4 + r;
      float mval = c1 * A1[Ao + (size_t)row * NN + col] +
                   c2 * bf2f(A2b[(size_t)row * NN + col]) + c3 * acc[i][r];
      pk |= (unsigned int)e4m3(mval) << (8 * r);
    }
    *(unsigned int*)(Mb + (size_t)col * NN + (tm * 64 + w * 16 + q * 4)) = pk;
  }
}

// ---------------------------------------------------------------------------
// Slow GEMMs (no A1T): proven scalar-load path, M8T epilogue.
// ---------------------------------------------------------------------------
__global__ __launch_bounds__(256) void gemm_a2_slow(
    const float* __restrict__ A1, unsigned short* __restrict__ A2) {
  const int b = blockIdx.x, tn = blockIdx.y, tm = blockIdx.z;
  const int tid = threadIdx.x, lane = tid & 63, w = tid >> 6;
  const int q = lane >> 4, ln = lane & 15;
  const size_t Ao = (size_t)b * NN * NN;
  f32x4 zero = {0.f, 0.f, 0.f, 0.f};
  f32x4 acc[4] = {zero, zero, zero, zero};
  const float* ap = A1 + Ao + (size_t)(tm * 64 + w * 16 + ln) * NN + q * 8;
  for (int k0 = 0; k0 < NN; k0 += 32) {
    f32x4 x0 = *(const f32x4*)(ap + k0);
    f32x4 x1 = *(const f32x4*)(ap + k0 + 4);
    union { bf16x8 v; unsigned int u[4]; } af;
    af.u[0] = pk_trunc(x0[1], x0[0]);
    af.u[1] = pk_trunc(x0[3], x0[2]);
    af.u[2] = pk_trunc(x1[1], x1[0]);
    af.u[3] = pk_trunc(x1[3], x1[2]);
#pragma unroll
    for (int i = 0; i < 4; ++i) {
      bf16x8 bv;
#pragma unroll
      for (int j = 0; j < 8; ++j)
        bv[j] = (short)f2bf(A1[Ao + (size_t)(k0 + q * 8 + j) * NN + tn * 64 + i * 16 + ln]);
      acc[i] = __builtin_amdgcn_mfma_f32_16x16x32_bf16(af.v, bv, acc[i], 0, 0, 0);
    }
  }
  unsigned short* Cb = A2 + Ao;
#pragma unroll
  for (int i = 0; i < 4; ++i) {
    int col = tn * 64 + i * 16 + ln;
#pragma unroll
    for (int r = 0; r < 4; ++r) {
      int row = tm * 64 + w * 16 + q * 4 + r;
      Cb[(size_t)row * NN + col] = f2bf(acc[i][r]);
    }
  }
}

__global__ __launch_bounds__(256) void gemm_m_slow(
    const float* __restrict__ A1, const unsigned short* __restrict__ A2,
    unsigned char* __restrict__ M8T) {
  const int b = blockIdx.x, tn = blockIdx.y, tm = blockIdx.z;
  const int tid = threadIdx.x, lane = tid & 63, w = tid >> 6;
  const int q = lane >> 4, ln = lane & 15;
  const size_t Ao = (size_t)b * NN * NN;
  const unsigned short* A2b = A2 + Ao;
  f32x4 zero = {0.f, 0.f, 0.f, 0.f};
  f32x4 acc[4] = {zero, zero, zero, zero};
  const unsigned short* ap = A2b + (size_t)(tm * 64 + w * 16 + ln) * NN + q * 8;
  for (int k0 = 0; k0 < NN; k0 += 32) {
    bf16x8 af = *(const bf16x8*)(ap + k0);
#pragma unroll
    for (int i = 0; i < 4; ++i) {
      bf16x8 bv;
#pragma unroll
      for (int j = 0; j < 8; ++j)
        bv[j] = (short)f2bf(A1[Ao + (size_t)(k0 + q * 8 + j) * NN + tn * 64 + i * 16 + ln]);
      acc[i] = __builtin_amdgcn_mfma_f32_16x16x32_bf16(af, bv, acc[i], 0, 0, 0);
    }
  }
  const float c1 = 1048576.f / (3.f * 512.f * 512.f);
  const float c2 = c1 / 512.f;
  const float c3 = c2 / 512.f;
  unsigned char* Mb = M8T + Ao;
#pragma unroll
  for (int i = 0; i < 4; ++i) {
    int col = tn * 64 + i * 16 + ln;
    unsigned int pk = 0;
#pragma unroll
    for (int r = 0; r < 4; ++r) {
      int row = tm * 64 + w * 16 + q * 4 + r;
      float mval = c1 * A1[Ao + (size_t)row * NN + col] +
                   c2 * bf2f(A2b[(size_t)row * NN + col]) + c3 * acc[i][r];
      pk |= (unsigned int)e4m3(mval) << (8 * r);
    }
    *(unsigned int*)(Mb + (size_t)col * NN + (tm * 64 + w * 16 + q * 4)) = pk;
  }
}

// ---------------------------------------------------------------------------
// Probe: HW-verify K=128 MX layout + unity scales. (Passed on this HW, r7.)
// ---------------------------------------------------------------------------
__global__ __launch_bounds__(64) void probe_kernel(int* __restrict__ flag) {
  const int lane = threadIdx.x, q = lane >> 4, n = lane & 15;
  __shared__ unsigned char A8[128];
  __shared__ unsigned char B8[128 * 16];
  for (int k = lane; k < 128; k += 64) A8[k] = (unsigned char)(8 + ((k * 37 + 11) % 56));
  for (int i = lane; i < 2048; i += 64)
    B8[i] = (unsigned char)(((i & 1) ? 0x80 : 0) | (8 + ((i * 23 + 5) % 56)));
  __syncthreads();
  union { i32x8 v; unsigned char b[32]; } af, bf;
#pragma unroll
  for (int j = 0; j < 32; ++j) {
    af.b[j] = A8[q * 32 + j];
    bf.b[j] = B8[(q * 32 + j) * 16 + n];
  }
  f32x4 acc = {0.f, 0.f, 0.f, 0.f};
  acc = __builtin_amdgcn_mfma_scale_f32_16x16x128_f8f6f4(af.v, bf.v, acc, 0, 0,
                                                         0, 127, 0, 127);
  float ref = 0.f;
  for (int k = 0; k < 128; ++k) ref += dec8(A8[k]) * dec8(B8[k * 16 + n]);
  int ok = 1;
#pragma unroll
  for (int r = 0; r < 4; ++r)
    ok &= (fabsf(acc[r] - ref) <= 1e-3f * fmaxf(fabsf(ref), 1.f)) ? 1 : 0;
  unsigned long long bal = __ballot(ok);
  if (lane == 0) *flag = (bal == ~0ull) ? 1 : 0;
}

// ---------------------------------------------------------------------------
// Scan: r7 structure; Phase-B dots moved to proven K=32 fp8 MFMAs (ub/uf
// hi+lo quantized, nrec/nsend hi+lo frags in regs); emb rows LDS-cached bf16;
// M frags built from M8T [col][k] with contiguous loads.
// ---------------------------------------------------------------------------
__global__ __launch_bounds__(512, 2) void scan_kernel(
    const int* __restrict__ skills, const int* __restrict__ times,
    const float* __restrict__ labels, const float* __restrict__ emb,
    const float* __restrict__ ub0g, const float* __restrict__ uf0g,
    const float* __restrict__ w1g, const float* __restrict__ b1g,
    const float* __restrict__ w2g, const float* __restrict__ b2g,
    const float* __restrict__ wfg, const float* __restrict__ bfg,
    const float* __restrict__ wbg, const float* __restrict__ bbg,
    const unsigned char* __restrict__ M8T, const int* __restrict__ flag,
    float* __restrict__ out) {
  const int b = blockIdx.x;
  const int t = threadIdx.x;
  const int lane = t & 63, w = t >> 6, q = lane >> 4, ln = lane & 15;

  __shared__ __align__(32) unsigned char lp8[NN];
  __shared__ __align__(8) unsigned char uq8[4][DD];  // ubHi,ubLo,ufHi,ufLo
  __shared__ float ub[DD], uf[DD];
  __shared__ float delta_s[NSTEP], label_s[NSTEP];
  __shared__ int skill_s[NSTEP];
  __shared__ float hp[16][33];
  __shared__ float w1t[DD * 5 * DD];
  __shared__ float w2t[DD * DD], wft[DD * DD], wbt[DD * DD];
  __shared__ float b1s[DD], b2s[DD], bfs[DD], bbs[DD];
  __shared__ unsigned short embS[NSTEP * 64];  // bf16 skill rows

  const int use_mx = *flag;

  for (int idx = t; idx < DD * DD * 5; idx += 512) {
    int o = idx / 160, rem = idx % 160;
    w1t[rem * 32 + o] = w1g[idx];
  }
  for (int idx = t; idx < DD * DD; idx += 512) {
    int o = idx >> 5, c = idx & 31;
    w2t[c * 32 + o] = w2g[idx];
    wft[c * 32 + o] = wfg[idx];
    wbt[c * 32 + o] = wbg[idx];
  }
  if (t < DD) {
    b1s[t] = b1g[t]; b2s[t] = b2g[t];
    bfs[t] = bfg[t]; bbs[t] = bbg[t];
    float vb = ub0g[b * DD + t], vf = uf0g[b * DD + t];
    ub[t] = vb; uf[t] = vf;
    unsigned char hb = e4m3(vb), hf = e4m3(vf);
    uq8[0][t] = hb; uq8[1][t] = e4m3(256.f * (vb - dec8(hb)));
    uq8[2][t] = hf; uq8[3][t] = e4m3(256.f * (vf - dec8(hf)));
  }
  for (int i = t; i < NSTEP; i += 512) {
    int dt_ = times[b * TTOT + i + 1] - times[b * TTOT + i];
    if (dt_ < 0) dt_ = -dt_;
    delta_s[i] = __logf((float)dt_ + 1e-6f) * 0.6213349345596119f;  // 1/ln 5
    label_s[i] = labels[b * TTOT + i + 1];
    skill_s[i] = skills[b * TTOT + i + 1];
  }
  __syncthreads();
  // emb rows for each step's skill -> LDS (bf16)
  for (int idx = t; idx < NSTEP * 64; idx += 512) {
    int st = idx >> 6, c = idx & 63;
    embS[idx] = f2bf(emb[(size_t)skill_s[st] * 64 + c]);
  }

  // M fragments from M8T[col][k]: contiguous per-lane loads, 128 VGPRs
  union MU { i32x8 v; long l[4]; };
  MU mreg[16];
  {
    const unsigned char* Mb = M8T + (size_t)b * NN * NN;
    if (use_mx) {
#pragma unroll
      for (int c = 0; c < 4; ++c)
#pragma unroll
        for (int i = 0; i < 4; ++i)
          mreg[c * 4 + i].v = *(const i32x8*)(
              Mb + (size_t)((w * 4 + i) * 16 + ln) * NN + c * 128 + q * 32);
    } else {
#pragma unroll
      for (int c = 0; c < 16; ++c)
#pragma unroll
        for (int i = 0; i < 4; ++i)
          mreg[c].l[i] = *(const long*)(
              Mb + (size_t)((w * 4 + i) * 16 + ln) * NN + c * 32 + q * 8);
    }
  }

  // nrec/nsend B-frags (hi+lo, x16 scale) for this wave's col groups
  union LU { long l; unsigned char c8[8]; };
  LU recHi[4], recLo[4], sendHi[4], sendLo[4];
#pragma unroll
  for (int i = 0; i < 4; ++i) {
    const float* er = emb + (size_t)((w * 4 + i) * 16 + ln) * 64;
#pragma unroll
    for (int j = 0; j < 8; ++j) {
      float rv = 16.f * er[32 + q * 8 + j];
      float sv = 16.f * er[q * 8 + j];
      unsigned char rh = e4m3(rv), sh = e4m3(sv);
      recHi[i].c8[j] = rh;
      recLo[i].c8[j] = e4m3(256.f * (rv - dec8(rh)));
      sendHi[i].c8[j] = sh;
      sendLo[i].c8[j] = e4m3(256.f * (sv - dec8(sh)));
    }
  }

  // initial last_perf / node_last_forget (one-time scalar dots)
  float rlp = 0.f, rnlf = 0.f;
  {
    const float* er = emb + (size_t)t * 64;
#pragma unroll
    for (int c = 0; c < DD; ++c) {
      rlp += ub0g[b * DD + c] * er[32 + c];
      rnlf += uf0g[b * DD + c] * er[c];
    }
  }
  lp8[t] = e4m3(rlp);
  __syncthreads();

  for (int step = 0; step < NSTEP; ++step) {
    // ---- Phase A: wave0 MLP (new ub/uf) || all waves: M matvec ----
    if (step && w == 0) {
      int o = lane & 31, half = lane >> 5;
      float part = 0.f;
#pragma unroll
      for (int s2 = 0; s2 < 8; ++s2) part += hp[half * 8 + s2][o];
      float h = b1s[o] + part + __shfl_xor(part, 32);
      h = fmaxf(h, 0.f);
      float up = 0.f;
#pragma unroll
      for (int cc = 0; cc < 16; ++cc) {
        float hv0 = rlane(h, cc), hv1 = rlane(h, 16 + cc);
        up += (half ? hv1 : hv0) * w2t[(half * 16 + cc) * 32 + o];
      }
      float uu = b2s[o] + up + __shfl_xor(up, 32);
      const float* wsel = half ? wbt : wft;
      float aac = half ? bbs[o] : bfs[o];
#pragma unroll
      for (int c = 0; c < DD; ++c) aac += rlane(uu, c) * wsel[c * 32 + o];
      float val = 1.f - 2.f / (1.f + __expf(2.f * aac));
      unsigned char vh = e4m3(val);
      unsigned char vl = e4m3(256.f * (val - dec8(vh)));
      if (half) { ub[o] = val; uq8[0][o] = vh; uq8[1][o] = vl; }
      else      { uf[o] = val; uq8[2][o] = vh; uq8[3][o] = vl; }
    }
    f32x4 zero = {0.f, 0.f, 0.f, 0.f};
    f32x4 acc[4] = {zero, zero, zero, zero};
    if (use_mx) {
#pragma unroll
      for (int c = 0; c < 4; ++c) {
        i32x8 af = *(const i32x8*)(&lp8[c * 128 + q * 32]);
#pragma unroll
        for (int i = 0; i < 4; ++i)
          acc[i] = __builtin_amdgcn_mfma_scale_f32_16x16x128_f8f6f4(
              af, mreg[c * 4 + i].v, acc[i], 0, 0, 0, 127, 0, 127);
      }
    } else {
#pragma unroll
      for (int c = 0; c < 16; ++c) {
        long af = *(const long*)(&lp8[c * 32 + q * 8]);
#pragma unroll
        for (int i = 0; i < 4; ++i)
          acc[i] = __builtin_amdgcn_mfma_f32_16x16x32_fp8_fp8(af, mreg[c].l[i],
                                                              acc[i], 0, 0, 0);
      }
    }
    float spatial = ((q & 2) ? ((q & 1) ? acc[3][0] : acc[2][0])
                             : ((q & 1) ? acc[1][0] : acc[0][0])) * 0x1p-20f;
    __syncthreads();  // sync1: ub/uf + uq8 ready; lp8 reads done

    // ---- Phase B: ncb/nlf on the matrix pipe (proven K=32 fp8 path) ----
    long aubh = *(const long*)(&uq8[0][q * 8]);
    long aubl = *(const long*)(&uq8[1][q * 8]);
    long aufh = *(const long*)(&uq8[2][q * 8]);
    long aufl = *(const long*)(&uq8[3][q * 8]);
    f32x4 hh[4], mm[4], nh[4], nm[4];
#pragma unroll
    for (int i = 0; i < 4; ++i) {
      hh[i] = __builtin_amdgcn_mfma_f32_16x16x32_fp8_fp8(aubh, recHi[i].l, zero, 0, 0, 0);
      mm[i] = __builtin_amdgcn_mfma_f32_16x16x32_fp8_fp8(aubl, recHi[i].l, zero, 0, 0, 0);
      mm[i] = __builtin_amdgcn_mfma_f32_16x16x32_fp8_fp8(aubh, recLo[i].l, mm[i], 0, 0, 0);
      nh[i] = __builtin_amdgcn_mfma_f32_16x16x32_fp8_fp8(aufh, sendHi[i].l, zero, 0, 0, 0);
      nm[i] = __builtin_amdgcn_mfma_f32_16x16x32_fp8_fp8(aufl, sendHi[i].l, zero, 0, 0, 0);
      nm[i] = __builtin_amdgcn_mfma_f32_16x16x32_fp8_fp8(aufh, sendLo[i].l, nm[i], 0, 0, 0);
    }
    float hhv = (q & 2) ? ((q & 1) ? hh[3][0] : hh[2][0]) : ((q & 1) ? hh[1][0] : hh[0][0]);
    float mmv = (q & 2) ? ((q & 1) ? mm[3][0] : mm[2][0]) : ((q & 1) ? mm[1][0] : mm[0][0]);
    float nhv = (q & 2) ? ((q & 1) ? nh[3][0] : nh[2][0]) : ((q & 1) ? nh[1][0] : nh[0][0]);
    float nmv = (q & 2) ? ((q & 1) ? nm[3][0] : nm[2][0]) : ((q & 1) ? nm[1][0] : nm[0][0]);
    float ncb = (hhv + mmv * 0.00390625f) * 0.0625f;
    float nlfn = (nhv + nmv * 0.00390625f) * 0.0625f;

    float e = __expf(-delta_s[step] * 0.1f * rnlf) * rlp;
    float cur = 1.f / (1.f + __expf(-(ncb + e + spatial)));

    {  // MLP h partials (512 threads, LDS-only inputs)
      int o = t & 31, s = t >> 5;
      float lab = label_s[step];
      const unsigned short* es = &embS[step * 64];
      float hpart = 0.f;
#pragma unroll
      for (int cc = 0; cc < 2; ++cc) {
        int c = (s << 1) + cc;
        const float* wrow = &w1t[(c * 5) * 32 + o];
        float rs = bf2f(es[c]);        // node_send[sk][c]
        float rr = bf2f(es[32 + c]);   // node_rec[sk][c]
        hpart += ub[c] * wrow[0] + uf[c] * wrow[32] + lab * wrow[64] +
                 rr * wrow[96] + rs * wrow[128];
      }
      hp[s][o] = hpart;
    }

    rlp = cur;
    rnlf = nlfn;
    lp8[t] = e4m3(cur);
    if (t == skill_s[step]) out[step * BSZ + b] = cur;
    __syncthreads();  // sync2: lp8/hp ready for next step
  }
}

extern "C" void kernel_launch(void* const* d_in, const int* in_sizes, int n_in,
                              void* d_out, int out_size, void* d_ws, size_t ws_size,
                              hipStream_t stream) {
  (void)in_sizes; (void)n_in; (void)out_size;
  const int* skills = (const int*)d_in[0];
  const int* times = (const int*)d_in[1];
  const float* labels = (const float*)d_in[2];
  const float* adj = (const float*)d_in[3];
  const float* emb = (const float*)d_in[4];

  const size_t mat = (size_t)BSZ * NN * NN;  // 16,777,216
  char* base = (char*)d_ws;
  unsigned char* M8T = (unsigned char*)base;
  unsigned short* A2 = (unsigned short*)(base + mat);
  int use_fast;
  unsigned short* A1T = nullptr;
  int* flag;
  if (ws_size >= 5 * mat + 4) {  // 83,886,084 (proven: ws >= 100.7 MB in r7)
    use_fast = 1;
    A1T = (unsigned short*)(base + 3 * mat);
    flag = (int*)(base + 5 * mat);
  } else {
    use_fast = 0;
    flag = (int*)(base + 3 * mat);
  }

  dim3 gg(BSZ, 8, 8), gb(256);
  if (use_fast) {
    transpose_kernel<<<gg, gb, 0, stream>>>(adj, A1T);
    gemm_a2_fast<<<gg, gb, 0, stream>>>(adj, A1T, A2);
    gemm_m_fast<<<gg, gb, 0, stream>>>(adj, A1T, A2, M8T);
  } else {
    gemm_a2_slow<<<gg, gb, 0, stream>>>(adj, A2);
    gemm_m_slow<<<gg, gb, 0, stream>>>(adj, A2, M8T);
  }
  probe_kernel<<<dim3(1), dim3(64), 0, stream>>>(flag);
  scan_kernel<<<dim3(BSZ), dim3(512), 0, stream>>>(
      skills, times, labels, emb, (const float*)d_in[5], (const float*)d_in[6],
      (const float*)d_in[7], (const float*)d_in[8], (const float*)d_in[9],
      (const float*)d_in[10], (const float*)d_in[11], (const float*)d_in[12],
      (const float*)d_in[13], (const float*)d_in[14], M8T, flag, (float*)d_out);
}